// Round 12
// baseline (439.559 us; speedup 1.0000x reference)
//
#include <hip/hip_runtime.h>

typedef unsigned short u16;
typedef unsigned int u32;
typedef __attribute__((ext_vector_type(8))) u16 u16x8;
typedef __attribute__((ext_vector_type(8))) __bf16 bf16x8;
typedef __attribute__((ext_vector_type(4))) float f32x4;

#define CIN 128
#define NB 4
#define NN 4096
#define KPTS 16
#define COUT 256
#define POSB 65536      // NN*KPTS
#define TOTPOS 262144   // NB*POSB
#define CK 2304         // 9*256

__device__ __forceinline__ float bf2f(u16 u){ return __uint_as_float(((u32)u)<<16); }
__device__ __forceinline__ u16 f2bf(float f){
  u32 u = __float_as_uint(f);
  u32 r = (u + 0x7fffu + ((u>>16)&1u)) >> 16;   // RNE
  return (u16)r;
}

// ---- 1. pack conv_w with the U/V transform:
//   out = Wl@x_i + Wr@(x_j-x_i) = (Wl-Wr)@x_i + Wr@x_j
__global__ void pack_w_kernel(const float* __restrict__ w, u16* __restrict__ wp){
  int t = blockIdx.x*256 + threadIdx.x;
  if (t >= COUT*CK) return;
  int co = t / CK; int r = t - co*CK; int tap = r >> 8; int c = r & 255;
  float v;
  if (c < 128)
    v = w[(co*256 + c)*9 + tap] - w[(co*256 + 128 + c)*9 + tap];
  else
    v = w[(co*256 + c)*9 + tap];
  wp[t] = f2bf(v);
}

// ---- 2. transpose+cast x,y [B][128][4096] f32 -> xt,yt [B][4096][128] bf16
__global__ void transpose_cast_kernel(const float* __restrict__ x, const float* __restrict__ y,
                                      u16* __restrict__ xt, u16* __restrict__ yt){
  __shared__ u16 tile[2][32][65];
  int n0 = blockIdx.x*64, c0 = blockIdx.y*32, b = blockIdx.z;
  int t = threadIdx.x;
  int tn = t & 63, tc = t >> 6;
  #pragma unroll
  for (int i=0;i<8;++i){
    int c = tc*8 + i;
    size_t src = ((size_t)(b*CIN + c0 + c))*NN + n0 + tn;
    tile[0][c][tn] = f2bf(x[src]);
    tile[1][c][tn] = f2bf(y[src]);
  }
  __syncthreads();
  int tcc = t & 31, tnn = t >> 5;
  #pragma unroll
  for (int i=0;i<8;++i){
    int n = tnn*8 + i;
    size_t dst = ((size_t)(b*NN + n0 + n))*CIN + c0 + tcc;
    xt[dst] = tile[0][tcc][n];
    yt[dst] = tile[1][tcc][n];
  }
}

// element offset into a [row][32] bf16 tile with 16B-chunk XOR swizzle (read side)
#define SWZ(row, chunk) (((row)*32) + ((((chunk) ^ (((row)>>1)&3))) << 3))

// ---- 3. fused panel-gather + implicit-GEMM conv (BM=256 x BN=128, 512 threads/8 waves)
// r8 step skeleton: [vmcnt(N); s_barrier] -> ds_read frags -> stage G16 -> 16 MFMA.
// 8 waves halve per-wave work; 2 blocks/CU -> 16 waves/CU (4/SIMD) for latency hiding.
__global__ __launch_bounds__(512, 4) void conv_gemm_kernel(const u16* __restrict__ wp,
    const int* __restrict__ e, const u16* __restrict__ xt, const u16* __restrict__ yt,
    const u16* __restrict__ zrow, const float* __restrict__ bias,
    float* __restrict__ ssum, float* __restrict__ ssq, float* __restrict__ maxout){
  __shared__ u16 als[3*8192];    // A (weights) triple buffer, 256co x 32ch each (16KB/slot)
  __shared__ u16 pnl[2*8192];    // H panel double buffer, 192(+64 pad) rows x 32ch (16KB/copy)

  int ptile = blockIdx.x;                        // 0..2047
  int p0 = ptile * 128;
  int b = p0 >> 16;
  int pib0 = p0 & (POSB-1);
  int nb0 = pib0 >> 4;                           // 8 n's per block

  int t = threadIdx.x;                           // 0..511
  int lane = t & 63, wave = t >> 6;              // 8 waves
  int wr = wave >> 1, wc = wave & 1;             // wave grid 4x2: 64co x 64pos each
  int l15 = lane & 15, l4 = lane >> 4;

  const u16* xb = xt + ((size_t)b)*NN*CIN;
  const u16* yb = yt + ((size_t)b)*NN*CIN;

  // A staging: 2 G16/thread; instr i covers row i*128 + wave*16 + (lane>>2), phys chunk lane&3
  int rA0 = wave*16 + (lane>>2);
  int rA1 = rA0 + 128;
  int chA0 = (lane&3) ^ ((rA0>>1)&3);
  int chA1 = (lane&3) ^ ((rA1>>1)&3);
  int wu = __builtin_amdgcn_readfirstlane(wave) * 512;   // wave slice (elems) per instr-round
  const u16* pA0 = wp + (size_t)rA0*CK + chA0*8;
  const u16* pA1 = wp + (size_t)rA1*CK + chA1*8;

  // panel gather pointers (once per block): 2 rounds/thread; round j covers row j*128+(t>>2)
  const u16 *xp[2], *yp[2];
  { int tq4 = t >> 2;
    #pragma unroll
    for (int j=0;j<2;++j){
      int row = j*128 + tq4;                     // 0..255 (180..255 = pad/invalid)
      int lc = (t&3) ^ ((row>>1)&3);
      int q = (row*57) >> 10;                    // row/18 for row<192
      int kk = row - q*18 - 1;                   // -1..16
      int n2 = nb0 - 1 + q;
      bool valid = (row < 180) && ((unsigned)n2 < (unsigned)NN) && ((unsigned)kk < (unsigned)KPTS);
      int j0 = 0, j1 = 0;
      if (valid){ int eo = b*POSB + n2*16 + kk; j0 = e[eo]; j1 = e[TOTPOS + eo]; }
      xp[j] = (valid ? xb + (size_t)j1*CIN : zrow) + lc*8;
      yp[j] = (valid ? yb + (size_t)j0*CIN : zrow) + lc*8;
    }
  }

  auto G16 = [&](const u16* g, const u16* l){
    __builtin_amdgcn_global_load_lds((const __attribute__((address_space(1))) u32*)g,
                                     (__attribute__((address_space(3))) u32*)l, 16, 0, 0);
  };

  f32x4 acc[4][4];
  #pragma unroll
  for (int i=0;i<4;++i)
    #pragma unroll
    for (int j=0;j<4;++j) acc[i][j] = (f32x4){0.f,0.f,0.f,0.f};

  // prologue: P0(2), P1(2), A-tap0(2)->slot0, A-tap1(2)->slot1
  G16(xp[0],    &pnl[wu]);
  G16(xp[1],    &pnl[4096+wu]);
  G16(xp[0]+32, &pnl[8192+wu]);
  G16(xp[1]+32, &pnl[8192+4096+wu]);
  #pragma unroll
  for (int s=0; s<2; ++s){
    G16(pA0+s*256, &als[s*8192+wu]);
    G16(pA1+s*256, &als[s*8192+4096+wu]);
  }

  int aoff[4];
  #pragma unroll
  for (int f=0; f<4; ++f) aoff[f] = SWZ(wr*64 + f*16 + l15, l4);
  int wc72l15 = wc*72 + l15;

  // STEP: [vmcnt(N); s_barrier][ds_read frags][stage P(tau0) + A(t+2)][MFMA x16]
  // vmcnt: allow only step t-1's issues in flight (2, or 4 when t-1 had tau==0)
  #define STEP(TAU) { \
    if ((TAU)==1) asm volatile("s_waitcnt vmcnt(4)\n\ts_barrier" ::: "memory"); \
    else          asm volatile("s_waitcnt vmcnt(2)\n\ts_barrier" ::: "memory"); \
    bf16x8 af[4], bv[4]; \
    { const int abase = ((TAU)%3)*8192; \
      _Pragma("unroll") \
      for (int f=0; f<4; ++f) af[f] = *(bf16x8*)&als[abase + aoff[f]]; } \
    { const u16* pb = pnl + (c&1)*8192; \
      const int kbc = ((TAU)/3)*18 + ((TAU)%3); \
      _Pragma("unroll") \
      for (int f=0; f<4; ++f){ int r = wc72l15 + kbc + f*18; \
        bv[f] = *(bf16x8*)&pb[r*32 + ((l4 ^ ((r>>1)&3))<<3)]; } } \
    if ((TAU)==0){ int cc=(c+1)&7; int co32=(cc&3)*32; \
      const u16* s0=(cc<4?xp[0]:yp[0])+co32; \
      const u16* s1=(cc<4?xp[1]:yp[1])+co32; \
      int pd=((c+1)&1)*8192; \
      G16(s0,&pnl[pd+wu]); G16(s1,&pnl[pd+4096+wu]); } \
    { const int chs = (c + (((TAU)>=7)?1:0)) & 7; \
      const int koff = ((((TAU)+2)%9)*256) + (chs<<5); \
      const int sbase = (((TAU)+2)%3)*8192; \
      G16(pA0 + koff, &als[sbase + wu]); \
      G16(pA1 + koff, &als[sbase + 4096 + wu]); } \
    __builtin_amdgcn_s_setprio(1); \
    _Pragma("unroll") \
    for (int fm=0; fm<4; ++fm) \
      _Pragma("unroll") \
      for (int fn=0; fn<4; ++fn) \
        acc[fm][fn] = __builtin_amdgcn_mfma_f32_16x16x32_bf16(af[fm], bv[fn], acc[fm][fn], 0, 0, 0); \
    __builtin_amdgcn_s_setprio(0); \
  }

  for (int c = 0; c < 8; ++c){
    STEP(0) STEP(1) STEP(2) STEP(3) STEP(4) STEP(5) STEP(6) STEP(7) STEP(8)
  }
  #undef STEP

  asm volatile("s_waitcnt vmcnt(0)\n\ts_barrier" ::: "memory");  // drain tail stages before LDS reuse

  // ---- epilogue: bias + max over k (l15) + per-channel sum/sumsq
  float* fs = (float*)&als[0];           // fs[0..256) = sum, fs[256..512) = sumsq
  fs[t] = 0.f;
  __syncthreads();

  #pragma unroll
  for (int fm=0; fm<4; ++fm){
    #pragma unroll
    for (int j=0; j<4; ++j){
      int ch = wr*64 + fm*16 + l4*4 + j;           // = global co
      float bv2 = bias[ch];
      float s = 0.f, q = 0.f;
      float mv[4];
      #pragma unroll
      for (int fn=0; fn<4; ++fn){
        float v = acc[fm][fn][j] + bv2;
        s += v; q += v*v; mv[fn] = v;
      }
      #pragma unroll
      for (int o=1; o<16; o<<=1){
        s += __shfl_xor(s, o, 64);
        q += __shfl_xor(q, o, 64);
        #pragma unroll
        for (int fn=0; fn<4; ++fn) mv[fn] = fmaxf(mv[fn], __shfl_xor(mv[fn], o, 64));
      }
      if (l15 == 0){
        atomicAdd(&fs[ch], s);
        atomicAdd(&fs[256 + ch], q);
        size_t rowb = ((size_t)(b*COUT + ch)) << 12;
        #pragma unroll
        for (int fn=0; fn<4; ++fn)
          maxout[rowb + nb0 + wc*4 + fn] = mv[fn];
      }
    }
  }
  __syncthreads();
  if (t < 256) atomicAdd(&ssum[t], fs[t]);
  else         atomicAdd(&ssq[t-256], fs[t]);
}

// ---- 4. finalize BN scale/shift
__global__ void finalize_stats_kernel(const float* __restrict__ ssum, const float* __restrict__ ssq,
                                      const float* __restrict__ gamma, const float* __restrict__ beta,
                                      float* __restrict__ scale, float* __restrict__ shift){
  int co = threadIdx.x;
  float inv = 1.0f / (float)TOTPOS;
  float mean = ssum[co]*inv;
  float var = ssq[co]*inv - mean*mean;
  float sc = gamma[co] * rsqrtf(var + 1e-5f);
  scale[co] = sc;
  shift[co] = beta[co] - mean*sc;
}

// ---- 5. in-place BN + ReLU on maxout (valid since scale>0)
__global__ void bn_finish_kernel(float* __restrict__ out, const float* __restrict__ scale,
                                 const float* __restrict__ shift){
  int t = blockIdx.x*256 + threadIdx.x;
  int co = (t >> 12) & 255;
  float v = out[t];
  out[t] = fmaxf(fmaf(scale[co], v, shift[co]), 0.f);
}

extern "C" void kernel_launch(void* const* d_in, const int* in_sizes, int n_in,
                              void* d_out, int out_size, void* d_ws, size_t ws_size,
                              hipStream_t stream){
  const float* x = (const float*)d_in[0];
  const float* y = (const float*)d_in[1];
  const int*   e = (const int*)d_in[2];
  const float* w = (const float*)d_in[3];
  const float* bias = (const float*)d_in[4];
  const float* gamma = (const float*)d_in[5];
  const float* beta  = (const float*)d_in[6];
  float* out = (float*)d_out;

  char* ws = (char*)d_ws;                  // total footprint: ~9.6 MB
  u16*   wp    = (u16*)(ws);               // 1,179,648 B
  float* ssum  = (float*)(ws + 1179648);   // 1 KB
  float* ssq   = (float*)(ws + 1180672);   // 1 KB
  u16*   zrow  = (u16*)(ws + 1181696);     // 1 KB zero row
  float* scale = (float*)(ws + 1182720);   // 1 KB
  float* shift = (float*)(ws + 1183744);   // 1 KB
  u16*   xt    = (u16*)(ws + 1184768);     // 4 MB
  u16*   yt    = (u16*)(ws + 5379072);     // 4 MB  (end: 9,573,376)

  hipMemsetAsync(ssum, 0, 3072, stream);   // zero ssum+ssq+zrow every call (deterministic)

  pack_w_kernel<<<2304, 256, 0, stream>>>(w, wp);
  dim3 tg(NN/64, CIN/32, NB);
  transpose_cast_kernel<<<tg, 256, 0, stream>>>(x, y, xt, yt);
  conv_gemm_kernel<<<2048, 512, 0, stream>>>(wp, e, xt, yt, zrow, bias, ssum, ssq, out);
  finalize_stats_kernel<<<1, COUT, 0, stream>>>(ssum, ssq, gamma, beta, scale, shift);
  bn_finish_kernel<<<out_size/256, 256, 0, stream>>>(out, scale, shift);
}

// Round 13
// 364.811 us; speedup vs baseline: 1.2049x; 1.2049x over previous
//
#include <hip/hip_runtime.h>

typedef unsigned short u16;
typedef unsigned int u32;
typedef __attribute__((ext_vector_type(8))) u16 u16x8;
typedef __attribute__((ext_vector_type(8))) __bf16 bf16x8;
typedef __attribute__((ext_vector_type(4))) float f32x4;

#define CIN 128
#define NB 4
#define NN 4096
#define KPTS 16
#define COUT 256
#define POSB 65536      // NN*KPTS
#define TOTPOS 262144   // NB*POSB
#define CK 2304         // 9*256

__device__ __forceinline__ float bf2f(u16 u){ return __uint_as_float(((u32)u)<<16); }
__device__ __forceinline__ u16 f2bf(float f){
  u32 u = __float_as_uint(f);
  u32 r = (u + 0x7fffu + ((u>>16)&1u)) >> 16;   // RNE
  return (u16)r;
}

// ---- 1. pack conv_w with the U/V transform:
//   out = Wl@x_i + Wr@(x_j-x_i) = (Wl-Wr)@x_i + Wr@x_j
__global__ void pack_w_kernel(const float* __restrict__ w, u16* __restrict__ wp){
  int t = blockIdx.x*256 + threadIdx.x;
  if (t >= COUT*CK) return;
  int co = t / CK; int r = t - co*CK; int tap = r >> 8; int c = r & 255;
  float v;
  if (c < 128)
    v = w[(co*256 + c)*9 + tap] - w[(co*256 + 128 + c)*9 + tap];
  else
    v = w[(co*256 + c)*9 + tap];
  wp[t] = f2bf(v);
}

// ---- 2. transpose+cast x,y [B][128][4096] f32 -> xt,yt [B][4096][128] bf16
__global__ void transpose_cast_kernel(const float* __restrict__ x, const float* __restrict__ y,
                                      u16* __restrict__ xt, u16* __restrict__ yt){
  __shared__ u16 tile[2][32][65];
  int n0 = blockIdx.x*64, c0 = blockIdx.y*32, b = blockIdx.z;
  int t = threadIdx.x;
  int tn = t & 63, tc = t >> 6;
  #pragma unroll
  for (int i=0;i<8;++i){
    int c = tc*8 + i;
    size_t src = ((size_t)(b*CIN + c0 + c))*NN + n0 + tn;
    tile[0][c][tn] = f2bf(x[src]);
    tile[1][c][tn] = f2bf(y[src]);
  }
  __syncthreads();
  int tcc = t & 31, tnn = t >> 5;
  #pragma unroll
  for (int i=0;i<8;++i){
    int n = tnn*8 + i;
    size_t dst = ((size_t)(b*NN + n0 + n))*CIN + c0 + tcc;
    xt[dst] = tile[0][tcc][n];
    yt[dst] = tile[1][tcc][n];
  }
}

// element offset into a [row][32] bf16 tile with 16B-chunk XOR swizzle (read side)
#define SWZ(row, chunk) (((row)*32) + ((((chunk) ^ (((row)>>1)&3))) << 3))

// ---- 3. fused panel-gather + implicit-GEMM conv (BM=256 x BN=128, 512 threads/8 waves)
// r8 step skeleton: [vmcnt(N); s_barrier] -> ds_read frags -> stage G16 -> 16 MFMA.
// launch_bounds(512,2): VGPR cap >=128 so acc stays in registers (r12's (512,4)
// capped at 64 VGPR and spilled acc to scratch: 600MB FETCH, the whole regression).
__global__ __launch_bounds__(512, 2) void conv_gemm_kernel(const u16* __restrict__ wp,
    const int* __restrict__ e, const u16* __restrict__ xt, const u16* __restrict__ yt,
    const u16* __restrict__ zrow, const float* __restrict__ bias,
    float* __restrict__ ssum, float* __restrict__ ssq, float* __restrict__ maxout){
  __shared__ u16 als[3*8192];    // A (weights) triple buffer, 256co x 32ch each (16KB/slot)
  __shared__ u16 pnl[2*8192];    // H panel double buffer, 192(+64 pad) rows x 32ch (16KB/copy)

  int ptile = blockIdx.x;                        // 0..2047
  int p0 = ptile * 128;
  int b = p0 >> 16;
  int pib0 = p0 & (POSB-1);
  int nb0 = pib0 >> 4;                           // 8 n's per block

  int t = threadIdx.x;                           // 0..511
  int lane = t & 63, wave = t >> 6;              // 8 waves
  int wr = wave >> 1, wc = wave & 1;             // wave grid 4x2: 64co x 64pos each
  int l15 = lane & 15, l4 = lane >> 4;

  const u16* xb = xt + ((size_t)b)*NN*CIN;
  const u16* yb = yt + ((size_t)b)*NN*CIN;

  // A staging: 2 G16/thread; instr i covers row i*128 + wave*16 + (lane>>2), phys chunk lane&3
  int rA0 = wave*16 + (lane>>2);
  int rA1 = rA0 + 128;
  int chA0 = (lane&3) ^ ((rA0>>1)&3);
  int chA1 = (lane&3) ^ ((rA1>>1)&3);
  int wu = __builtin_amdgcn_readfirstlane(wave) * 512;   // wave slice (elems) per instr-round
  const u16* pA0 = wp + (size_t)rA0*CK + chA0*8;
  const u16* pA1 = wp + (size_t)rA1*CK + chA1*8;

  // panel gather pointers (once per block): 2 rounds/thread; round j covers row j*128+(t>>2)
  const u16 *xp[2], *yp[2];
  { int tq4 = t >> 2;
    #pragma unroll
    for (int j=0;j<2;++j){
      int row = j*128 + tq4;                     // 0..255 (180..255 = pad/invalid)
      int lc = (t&3) ^ ((row>>1)&3);
      int q = (row*57) >> 10;                    // row/18 for row<192
      int kk = row - q*18 - 1;                   // -1..16
      int n2 = nb0 - 1 + q;
      bool valid = (row < 180) && ((unsigned)n2 < (unsigned)NN) && ((unsigned)kk < (unsigned)KPTS);
      int j0 = 0, j1 = 0;
      if (valid){ int eo = b*POSB + n2*16 + kk; j0 = e[eo]; j1 = e[TOTPOS + eo]; }
      xp[j] = (valid ? xb + (size_t)j1*CIN : zrow) + lc*8;
      yp[j] = (valid ? yb + (size_t)j0*CIN : zrow) + lc*8;
    }
  }

  auto G16 = [&](const u16* g, const u16* l){
    __builtin_amdgcn_global_load_lds((const __attribute__((address_space(1))) u32*)g,
                                     (__attribute__((address_space(3))) u32*)l, 16, 0, 0);
  };

  f32x4 acc[4][4];
  #pragma unroll
  for (int i=0;i<4;++i)
    #pragma unroll
    for (int j=0;j<4;++j) acc[i][j] = (f32x4){0.f,0.f,0.f,0.f};

  // prologue: P0(2), P1(2), A-tap0(2)->slot0, A-tap1(2)->slot1
  G16(xp[0],    &pnl[wu]);
  G16(xp[1],    &pnl[4096+wu]);
  G16(xp[0]+32, &pnl[8192+wu]);
  G16(xp[1]+32, &pnl[8192+4096+wu]);
  #pragma unroll
  for (int s=0; s<2; ++s){
    G16(pA0+s*256, &als[s*8192+wu]);
    G16(pA1+s*256, &als[s*8192+4096+wu]);
  }

  int aoff[4];
  #pragma unroll
  for (int f=0; f<4; ++f) aoff[f] = SWZ(wr*64 + f*16 + l15, l4);
  int wc72l15 = wc*72 + l15;

  // STEP: [vmcnt(N); s_barrier][ds_read frags][stage P(tau0) + A(t+2)][MFMA x16]
  // vmcnt: allow only step t-1's issues in flight (2, or 4 when t-1 had tau==0)
  #define STEP(TAU) { \
    if ((TAU)==1) asm volatile("s_waitcnt vmcnt(4)\n\ts_barrier" ::: "memory"); \
    else          asm volatile("s_waitcnt vmcnt(2)\n\ts_barrier" ::: "memory"); \
    bf16x8 af[4], bv[4]; \
    { const int abase = ((TAU)%3)*8192; \
      _Pragma("unroll") \
      for (int f=0; f<4; ++f) af[f] = *(bf16x8*)&als[abase + aoff[f]]; } \
    { const u16* pb = pnl + (c&1)*8192; \
      const int kbc = ((TAU)/3)*18 + ((TAU)%3); \
      _Pragma("unroll") \
      for (int f=0; f<4; ++f){ int r = wc72l15 + kbc + f*18; \
        bv[f] = *(bf16x8*)&pb[r*32 + ((l4 ^ ((r>>1)&3))<<3)]; } } \
    if ((TAU)==0){ int cc=(c+1)&7; int co32=(cc&3)*32; \
      const u16* s0=(cc<4?xp[0]:yp[0])+co32; \
      const u16* s1=(cc<4?xp[1]:yp[1])+co32; \
      int pd=((c+1)&1)*8192; \
      G16(s0,&pnl[pd+wu]); G16(s1,&pnl[pd+4096+wu]); } \
    { const int chs = (c + (((TAU)>=7)?1:0)) & 7; \
      const int koff = ((((TAU)+2)%9)*256) + (chs<<5); \
      const int sbase = (((TAU)+2)%3)*8192; \
      G16(pA0 + koff, &als[sbase + wu]); \
      G16(pA1 + koff, &als[sbase + 4096 + wu]); } \
    __builtin_amdgcn_s_setprio(1); \
    _Pragma("unroll") \
    for (int fm=0; fm<4; ++fm) \
      _Pragma("unroll") \
      for (int fn=0; fn<4; ++fn) \
        acc[fm][fn] = __builtin_amdgcn_mfma_f32_16x16x32_bf16(af[fm], bv[fn], acc[fm][fn], 0, 0, 0); \
    __builtin_amdgcn_s_setprio(0); \
  }

  for (int c = 0; c < 8; ++c){
    STEP(0) STEP(1) STEP(2) STEP(3) STEP(4) STEP(5) STEP(6) STEP(7) STEP(8)
  }
  #undef STEP

  asm volatile("s_waitcnt vmcnt(0)\n\ts_barrier" ::: "memory");  // drain tail stages before LDS reuse

  // ---- epilogue: bias + max over k (l15) + per-channel sum/sumsq
  float* fs = (float*)&als[0];           // fs[0..256) = sum, fs[256..512) = sumsq
  fs[t] = 0.f;
  __syncthreads();

  #pragma unroll
  for (int fm=0; fm<4; ++fm){
    #pragma unroll
    for (int j=0; j<4; ++j){
      int ch = wr*64 + fm*16 + l4*4 + j;           // = global co
      float bv2 = bias[ch];
      float s = 0.f, q = 0.f;
      float mv[4];
      #pragma unroll
      for (int fn=0; fn<4; ++fn){
        float v = acc[fm][fn][j] + bv2;
        s += v; q += v*v; mv[fn] = v;
      }
      #pragma unroll
      for (int o=1; o<16; o<<=1){
        s += __shfl_xor(s, o, 64);
        q += __shfl_xor(q, o, 64);
        #pragma unroll
        for (int fn=0; fn<4; ++fn) mv[fn] = fmaxf(mv[fn], __shfl_xor(mv[fn], o, 64));
      }
      if (l15 == 0){
        atomicAdd(&fs[ch], s);
        atomicAdd(&fs[256 + ch], q);
        size_t rowb = ((size_t)(b*COUT + ch)) << 12;
        #pragma unroll
        for (int fn=0; fn<4; ++fn)
          maxout[rowb + nb0 + wc*4 + fn] = mv[fn];
      }
    }
  }
  __syncthreads();
  if (t < 256) atomicAdd(&ssum[t], fs[t]);
  else         atomicAdd(&ssq[t-256], fs[t]);
}

// ---- 4. finalize BN scale/shift
__global__ void finalize_stats_kernel(const float* __restrict__ ssum, const float* __restrict__ ssq,
                                      const float* __restrict__ gamma, const float* __restrict__ beta,
                                      float* __restrict__ scale, float* __restrict__ shift){
  int co = threadIdx.x;
  float inv = 1.0f / (float)TOTPOS;
  float mean = ssum[co]*inv;
  float var = ssq[co]*inv - mean*mean;
  float sc = gamma[co] * rsqrtf(var + 1e-5f);
  scale[co] = sc;
  shift[co] = beta[co] - mean*sc;
}

// ---- 5. in-place BN + ReLU on maxout (valid since scale>0)
__global__ void bn_finish_kernel(float* __restrict__ out, const float* __restrict__ scale,
                                 const float* __restrict__ shift){
  int t = blockIdx.x*256 + threadIdx.x;
  int co = (t >> 12) & 255;
  float v = out[t];
  out[t] = fmaxf(fmaf(scale[co], v, shift[co]), 0.f);
}

extern "C" void kernel_launch(void* const* d_in, const int* in_sizes, int n_in,
                              void* d_out, int out_size, void* d_ws, size_t ws_size,
                              hipStream_t stream){
  const float* x = (const float*)d_in[0];
  const float* y = (const float*)d_in[1];
  const int*   e = (const int*)d_in[2];
  const float* w = (const float*)d_in[3];
  const float* bias = (const float*)d_in[4];
  const float* gamma = (const float*)d_in[5];
  const float* beta  = (const float*)d_in[6];
  float* out = (float*)d_out;

  char* ws = (char*)d_ws;                  // total footprint: ~9.6 MB
  u16*   wp    = (u16*)(ws);               // 1,179,648 B
  float* ssum  = (float*)(ws + 1179648);   // 1 KB
  float* ssq   = (float*)(ws + 1180672);   // 1 KB
  u16*   zrow  = (u16*)(ws + 1181696);     // 1 KB zero row
  float* scale = (float*)(ws + 1182720);   // 1 KB
  float* shift = (float*)(ws + 1183744);   // 1 KB
  u16*   xt    = (u16*)(ws + 1184768);     // 4 MB
  u16*   yt    = (u16*)(ws + 5379072);     // 4 MB  (end: 9,573,376)

  hipMemsetAsync(ssum, 0, 3072, stream);   // zero ssum+ssq+zrow every call (deterministic)

  pack_w_kernel<<<2304, 256, 0, stream>>>(w, wp);
  dim3 tg(NN/64, CIN/32, NB);
  transpose_cast_kernel<<<tg, 256, 0, stream>>>(x, y, xt, yt);
  conv_gemm_kernel<<<2048, 512, 0, stream>>>(wp, e, xt, yt, zrow, bias, ssum, ssq, out);
  finalize_stats_kernel<<<1, COUT, 0, stream>>>(ssum, ssq, gamma, beta, scale, shift);
  bn_finish_kernel<<<out_size/256, 256, 0, stream>>>(out, scale, shift);
}

// Round 14
// 363.682 us; speedup vs baseline: 1.2086x; 1.0031x over previous
//
#include <hip/hip_runtime.h>

typedef unsigned short u16;
typedef unsigned int u32;
typedef __attribute__((ext_vector_type(8))) u16 u16x8;
typedef __attribute__((ext_vector_type(8))) __bf16 bf16x8;
typedef __attribute__((ext_vector_type(4))) float f32x4;

#define CIN 128
#define NB 4
#define NN 4096
#define KPTS 16
#define COUT 256
#define POSB 65536      // NN*KPTS
#define TOTPOS 262144   // NB*POSB
#define CK 2304         // 9*256

__device__ __forceinline__ float bf2f(u16 u){ return __uint_as_float(((u32)u)<<16); }
__device__ __forceinline__ u16 f2bf(float f){
  u32 u = __float_as_uint(f);
  u32 r = (u + 0x7fffu + ((u>>16)&1u)) >> 16;   // RNE
  return (u16)r;
}

// ---- 1. pack conv_w with the U/V transform:
//   out = Wl@x_i + Wr@(x_j-x_i) = (Wl-Wr)@x_i + Wr@x_j
__global__ void pack_w_kernel(const float* __restrict__ w, u16* __restrict__ wp){
  int t = blockIdx.x*256 + threadIdx.x;
  if (t >= COUT*CK) return;
  int co = t / CK; int r = t - co*CK; int tap = r >> 8; int c = r & 255;
  float v;
  if (c < 128)
    v = w[(co*256 + c)*9 + tap] - w[(co*256 + 128 + c)*9 + tap];
  else
    v = w[(co*256 + c)*9 + tap];
  wp[t] = f2bf(v);
}

// ---- 2. transpose+cast x,y [B][128][4096] f32 -> xt,yt [B][4096][128] bf16
__global__ void transpose_cast_kernel(const float* __restrict__ x, const float* __restrict__ y,
                                      u16* __restrict__ xt, u16* __restrict__ yt){
  __shared__ u16 tile[2][32][65];
  int n0 = blockIdx.x*64, c0 = blockIdx.y*32, b = blockIdx.z;
  int t = threadIdx.x;
  int tn = t & 63, tc = t >> 6;
  #pragma unroll
  for (int i=0;i<8;++i){
    int c = tc*8 + i;
    size_t src = ((size_t)(b*CIN + c0 + c))*NN + n0 + tn;
    tile[0][c][tn] = f2bf(x[src]);
    tile[1][c][tn] = f2bf(y[src]);
  }
  __syncthreads();
  int tcc = t & 31, tnn = t >> 5;
  #pragma unroll
  for (int i=0;i<8;++i){
    int n = tnn*8 + i;
    size_t dst = ((size_t)(b*NN + n0 + n))*CIN + c0 + tcc;
    xt[dst] = tile[0][tcc][n];
    yt[dst] = tile[1][tcc][n];
  }
}

// element offset into a [row][32] bf16 tile with 16B-chunk XOR swizzle (read side)
#define SWZ(row, chunk) (((row)*32) + ((((chunk) ^ (((row)>>1)&3))) << 3))

// ---- 3. fused panel-gather + implicit-GEMM conv (BM=256 x BN=128, 512 threads/8 waves)
// r8 step skeleton. LDS trimmed to 72KB (panel = true 192-row size, 12KB/copy) so
// TWO 512-thread blocks fit per CU -> 16 waves/CU (r13's 80KB forced 1 block/CU).
// Waves 4-7 issue their panel G16 twice (idempotent) to keep vmcnt counts uniform.
__global__ __launch_bounds__(512, 2) void conv_gemm_kernel(const u16* __restrict__ wp,
    const int* __restrict__ e, const u16* __restrict__ xt, const u16* __restrict__ yt,
    const u16* __restrict__ zrow, const float* __restrict__ bias,
    float* __restrict__ ssum, float* __restrict__ ssq, float* __restrict__ maxout){
  __shared__ u16 als[3*8192];    // A (weights) triple buffer, 256co x 32ch each (16KB/slot)
  __shared__ u16 pnl[2*6144];    // H panel double buffer, 192 rows x 32ch (12KB/copy)

  int ptile = blockIdx.x;                        // 0..2047
  int p0 = ptile * 128;
  int b = p0 >> 16;
  int pib0 = p0 & (POSB-1);
  int nb0 = pib0 >> 4;                           // 8 n's per block

  int t = threadIdx.x;                           // 0..511
  int lane = t & 63, wave = t >> 6;              // 8 waves
  int wr = wave >> 1, wc = wave & 1;             // wave grid 4x2: 64co x 64pos each
  int l15 = lane & 15, l4 = lane >> 4;

  const u16* xb = xt + ((size_t)b)*NN*CIN;
  const u16* yb = yt + ((size_t)b)*NN*CIN;

  // A staging: 2 G16/thread; instr s covers row s*128 + wave*16 + (lane>>2), phys chunk lane&3
  int rA0 = wave*16 + (lane>>2);
  int rA1 = rA0 + 128;
  int chA0 = (lane&3) ^ ((rA0>>1)&3);
  int chA1 = (lane&3) ^ ((rA1>>1)&3);
  int wuni = __builtin_amdgcn_readfirstlane(wave);
  int wu = wuni * 512;                           // A-stage wave slice (elems) per instr-round
  const u16* pA0 = wp + (size_t)rA0*CK + chA0*8;
  const u16* pA1 = wp + (size_t)rA1*CK + chA1*8;

  // panel staging: 768 tasks of 8 elems (192 rows x 4 chunks). Waves 0-3 take 2 tasks,
  // waves 4-7 take 1 task issued twice (uniform counts). dest = base + lane*8.
  int base0 = (wuni < 4) ? wuni*1024 : 4096 + (wuni-4)*512;
  int base1 = (wuni < 4) ? base0 + 512 : base0;
  int task0 = (base0 >> 3) + lane;
  int task1 = (base1 >> 3) + lane;

  const u16 *xq0, *yq0, *xq1, *yq1;
  {
    auto PSRC = [&](int task, const u16*& px, const u16*& py){
      int row = task >> 2;                       // 0..191
      int pc = task & 3;
      int lc = pc ^ ((row>>1)&3);                // inverse swizzle chunk
      int q = (row*57) >> 10;                    // row/18
      int kk = row - q*18 - 1;                   // -1..16
      int n2 = nb0 - 1 + q;
      bool valid = (row < 180) && ((unsigned)n2 < (unsigned)NN) && ((unsigned)kk < (unsigned)KPTS);
      int j0 = 0, j1 = 0;
      if (valid){ int eo = b*POSB + n2*16 + kk; j0 = e[eo]; j1 = e[TOTPOS + eo]; }
      px = (valid ? xb + (size_t)j1*CIN : zrow) + lc*8;
      py = (valid ? yb + (size_t)j0*CIN : zrow) + lc*8;
    };
    PSRC(task0, xq0, yq0);
    PSRC(task1, xq1, yq1);
  }

  auto G16 = [&](const u16* g, const u16* l){
    __builtin_amdgcn_global_load_lds((const __attribute__((address_space(1))) u32*)g,
                                     (__attribute__((address_space(3))) u32*)l, 16, 0, 0);
  };

  f32x4 acc[4][4];
  #pragma unroll
  for (int i=0;i<4;++i)
    #pragma unroll
    for (int j=0;j<4;++j) acc[i][j] = (f32x4){0.f,0.f,0.f,0.f};

  // prologue: P0(2), P1(2), A-tap0(2)->slot0, A-tap1(2)->slot1
  G16(xq0,    &pnl[base0]);
  G16(xq1,    &pnl[base1]);
  G16(xq0+32, &pnl[6144+base0]);
  G16(xq1+32, &pnl[6144+base1]);
  #pragma unroll
  for (int s=0; s<2; ++s){
    G16(pA0+s*256, &als[s*8192+wu]);
    G16(pA1+s*256, &als[s*8192+4096+wu]);
  }

  int aoff[4];
  #pragma unroll
  for (int f=0; f<4; ++f) aoff[f] = SWZ(wr*64 + f*16 + l15, l4);
  int wc72l15 = wc*72 + l15;

  // STEP: [vmcnt(N); s_barrier][ds_read frags][stage P(tau0) + A(t+2)][MFMA x16]
  // vmcnt: allow only step t-1's issues in flight (2, or 4 when t-1 had tau==0)
  #define STEP(TAU) { \
    if ((TAU)==1) asm volatile("s_waitcnt vmcnt(4)\n\ts_barrier" ::: "memory"); \
    else          asm volatile("s_waitcnt vmcnt(2)\n\ts_barrier" ::: "memory"); \
    bf16x8 af[4], bv[4]; \
    { const int abase = ((TAU)%3)*8192; \
      _Pragma("unroll") \
      for (int f=0; f<4; ++f) af[f] = *(bf16x8*)&als[abase + aoff[f]]; } \
    { const u16* pb = pnl + (c&1)*6144; \
      const int kbc = ((TAU)/3)*18 + ((TAU)%3); \
      _Pragma("unroll") \
      for (int f=0; f<4; ++f){ int r = wc72l15 + kbc + f*18; \
        bv[f] = *(bf16x8*)&pb[r*32 + ((l4 ^ ((r>>1)&3))<<3)]; } } \
    if ((TAU)==0){ int cc=(c+1)&7; int co32=(cc&3)*32; \
      const u16* s0=(cc<4?xq0:yq0)+co32; \
      const u16* s1=(cc<4?xq1:yq1)+co32; \
      int pd=((c+1)&1)*6144; \
      G16(s0,&pnl[pd+base0]); G16(s1,&pnl[pd+base1]); } \
    { const int chs = (c + (((TAU)>=7)?1:0)) & 7; \
      const int koff = ((((TAU)+2)%9)*256) + (chs<<5); \
      const int sbase = (((TAU)+2)%3)*8192; \
      G16(pA0 + koff, &als[sbase + wu]); \
      G16(pA1 + koff, &als[sbase + 4096 + wu]); } \
    __builtin_amdgcn_s_setprio(1); \
    _Pragma("unroll") \
    for (int fm=0; fm<4; ++fm) \
      _Pragma("unroll") \
      for (int fn=0; fn<4; ++fn) \
        acc[fm][fn] = __builtin_amdgcn_mfma_f32_16x16x32_bf16(af[fm], bv[fn], acc[fm][fn], 0, 0, 0); \
    __builtin_amdgcn_s_setprio(0); \
  }

  for (int c = 0; c < 8; ++c){
    STEP(0) STEP(1) STEP(2) STEP(3) STEP(4) STEP(5) STEP(6) STEP(7) STEP(8)
  }
  #undef STEP

  asm volatile("s_waitcnt vmcnt(0)\n\ts_barrier" ::: "memory");  // drain tail stages before LDS reuse

  // ---- epilogue: bias + max over k (l15) + per-channel sum/sumsq
  float* fs = (float*)&als[0];           // fs[0..256) = sum, fs[256..512) = sumsq
  fs[t] = 0.f;
  __syncthreads();

  #pragma unroll
  for (int fm=0; fm<4; ++fm){
    #pragma unroll
    for (int j=0; j<4; ++j){
      int ch = wr*64 + fm*16 + l4*4 + j;           // = global co
      float bv2 = bias[ch];
      float s = 0.f, q = 0.f;
      float mv[4];
      #pragma unroll
      for (int fn=0; fn<4; ++fn){
        float v = acc[fm][fn][j] + bv2;
        s += v; q += v*v; mv[fn] = v;
      }
      #pragma unroll
      for (int o=1; o<16; o<<=1){
        s += __shfl_xor(s, o, 64);
        q += __shfl_xor(q, o, 64);
        #pragma unroll
        for (int fn=0; fn<4; ++fn) mv[fn] = fmaxf(mv[fn], __shfl_xor(mv[fn], o, 64));
      }
      if (l15 == 0){
        atomicAdd(&fs[ch], s);
        atomicAdd(&fs[256 + ch], q);
        size_t rowb = ((size_t)(b*COUT + ch)) << 12;
        #pragma unroll
        for (int fn=0; fn<4; ++fn)
          maxout[rowb + nb0 + wc*4 + fn] = mv[fn];
      }
    }
  }
  __syncthreads();
  if (t < 256) atomicAdd(&ssum[t], fs[t]);
  else         atomicAdd(&ssq[t-256], fs[t]);
}

// ---- 4. finalize BN scale/shift
__global__ void finalize_stats_kernel(const float* __restrict__ ssum, const float* __restrict__ ssq,
                                      const float* __restrict__ gamma, const float* __restrict__ beta,
                                      float* __restrict__ scale, float* __restrict__ shift){
  int co = threadIdx.x;
  float inv = 1.0f / (float)TOTPOS;
  float mean = ssum[co]*inv;
  float var = ssq[co]*inv - mean*mean;
  float sc = gamma[co] * rsqrtf(var + 1e-5f);
  scale[co] = sc;
  shift[co] = beta[co] - mean*sc;
}

// ---- 5. in-place BN + ReLU on maxout (valid since scale>0)
__global__ void bn_finish_kernel(float* __restrict__ out, const float* __restrict__ scale,
                                 const float* __restrict__ shift){
  int t = blockIdx.x*256 + threadIdx.x;
  int co = (t >> 12) & 255;
  float v = out[t];
  out[t] = fmaxf(fmaf(scale[co], v, shift[co]), 0.f);
}

extern "C" void kernel_launch(void* const* d_in, const int* in_sizes, int n_in,
                              void* d_out, int out_size, void* d_ws, size_t ws_size,
                              hipStream_t stream){
  const float* x = (const float*)d_in[0];
  const float* y = (const float*)d_in[1];
  const int*   e = (const int*)d_in[2];
  const float* w = (const float*)d_in[3];
  const float* bias = (const float*)d_in[4];
  const float* gamma = (const float*)d_in[5];
  const float* beta  = (const float*)d_in[6];
  float* out = (float*)d_out;

  char* ws = (char*)d_ws;                  // total footprint: ~9.6 MB
  u16*   wp    = (u16*)(ws);               // 1,179,648 B
  float* ssum  = (float*)(ws + 1179648);   // 1 KB
  float* ssq   = (float*)(ws + 1180672);   // 1 KB
  u16*   zrow  = (u16*)(ws + 1181696);     // 1 KB zero row
  float* scale = (float*)(ws + 1182720);   // 1 KB
  float* shift = (float*)(ws + 1183744);   // 1 KB
  u16*   xt    = (u16*)(ws + 1184768);     // 4 MB
  u16*   yt    = (u16*)(ws + 5379072);     // 4 MB  (end: 9,573,376)

  hipMemsetAsync(ssum, 0, 3072, stream);   // zero ssum+ssq+zrow every call (deterministic)

  pack_w_kernel<<<2304, 256, 0, stream>>>(w, wp);
  dim3 tg(NN/64, CIN/32, NB);
  transpose_cast_kernel<<<tg, 256, 0, stream>>>(x, y, xt, yt);
  conv_gemm_kernel<<<2048, 512, 0, stream>>>(wp, e, xt, yt, zrow, bias, ssum, ssq, out);
  finalize_stats_kernel<<<1, COUT, 0, stream>>>(ssum, ssq, gamma, beta, scale, shift);
  bn_finish_kernel<<<out_size/256, 256, 0, stream>>>(out, scale, shift);
}

// Round 15
// 350.006 us; speedup vs baseline: 1.2559x; 1.0391x over previous
//
#include <hip/hip_runtime.h>

typedef unsigned short u16;
typedef unsigned int u32;
typedef __attribute__((ext_vector_type(8))) u16 u16x8;
typedef __attribute__((ext_vector_type(8))) __bf16 bf16x8;
typedef __attribute__((ext_vector_type(4))) float f32x4;

#define CIN 128
#define NB 4
#define NN 4096
#define KPTS 16
#define COUT 256
#define POSB 65536      // NN*KPTS
#define TOTPOS 262144   // NB*POSB
#define CK 2304         // 9*256

__device__ __forceinline__ float bf2f(u16 u){ return __uint_as_float(((u32)u)<<16); }
__device__ __forceinline__ u16 f2bf(float f){
  u32 u = __float_as_uint(f);
  u32 r = (u + 0x7fffu + ((u>>16)&1u)) >> 16;   // RNE
  return (u16)r;
}

// ---- 1. pack conv_w with the U/V transform:
//   out = Wl@x_i + Wr@(x_j-x_i) = (Wl-Wr)@x_i + Wr@x_j
__global__ void pack_w_kernel(const float* __restrict__ w, u16* __restrict__ wp){
  int t = blockIdx.x*256 + threadIdx.x;
  if (t >= COUT*CK) return;
  int co = t / CK; int r = t - co*CK; int tap = r >> 8; int c = r & 255;
  float v;
  if (c < 128)
    v = w[(co*256 + c)*9 + tap] - w[(co*256 + 128 + c)*9 + tap];
  else
    v = w[(co*256 + c)*9 + tap];
  wp[t] = f2bf(v);
}

// ---- 2. transpose+cast x,y [B][128][4096] f32 -> xt,yt [B][4096][128] bf16
__global__ void transpose_cast_kernel(const float* __restrict__ x, const float* __restrict__ y,
                                      u16* __restrict__ xt, u16* __restrict__ yt){
  __shared__ u16 tile[2][32][65];
  int n0 = blockIdx.x*64, c0 = blockIdx.y*32, b = blockIdx.z;
  int t = threadIdx.x;
  int tn = t & 63, tc = t >> 6;
  #pragma unroll
  for (int i=0;i<8;++i){
    int c = tc*8 + i;
    size_t src = ((size_t)(b*CIN + c0 + c))*NN + n0 + tn;
    tile[0][c][tn] = f2bf(x[src]);
    tile[1][c][tn] = f2bf(y[src]);
  }
  __syncthreads();
  int tcc = t & 31, tnn = t >> 5;
  #pragma unroll
  for (int i=0;i<8;++i){
    int n = tnn*8 + i;
    size_t dst = ((size_t)(b*NN + n0 + n))*CIN + c0 + tcc;
    xt[dst] = tile[0][tcc][n];
    yt[dst] = tile[1][tcc][n];
  }
}

// element offset into a [row][32] bf16 tile with 16B-chunk XOR swizzle (read side)
#define SWZ(row, chunk) (((row)*32) + ((((chunk) ^ (((row)>>1)&3))) << 3))

// ---- 3. fused panel-gather + implicit-GEMM conv + bias + (max over k) + BN stats
// r6 kernel VERBATIM except __launch_bounds__(256) -> (256,4): BM=128, 48KB LDS,
// so 3 blocks/CU fit by LDS; waves-per-eu=4 metadata requests the occupancy
// (r12-vs-r13 A/B showed the metadata drives co-residency; r12's spill avoided
// here since this kernel needs ~104 VGPR <= the 128 cap).
__global__ __launch_bounds__(256, 4) void conv_gemm_kernel(const u16* __restrict__ wp,
    const int* __restrict__ e, const u16* __restrict__ xt, const u16* __restrict__ yt,
    const u16* __restrict__ zrow, const float* __restrict__ bias,
    float* __restrict__ ssum, float* __restrict__ ssq, float* __restrict__ maxout){
  __shared__ u16 als[3*4096];    // A (weights) triple buffer, 128co x 32ch each
  __shared__ u16 pnl[2*6144];    // H panel double buffer, 192 rows x 32ch each

  int bid = blockIdx.x;
  int co_half = (bid >> 3) & 1;                 // pair same-ptile blocks 8 apart (same XCD)
  int ptile = (bid & 7) | ((bid >> 4) << 3);
  int p0 = ptile * 128;
  int b = p0 >> 16;
  int pib0 = p0 & (POSB-1);
  int nb0 = pib0 >> 4;                          // 8 n's per block

  int t = threadIdx.x;
  int lane = t & 63, wave = t >> 6;
  int wr = wave >> 1, wc = wave & 1;
  int co_base = co_half*128;
  int l15 = lane & 15, l4 = lane >> 4;

  const u16* xb = xt + ((size_t)b)*NN*CIN;
  const u16* yb = yt + ((size_t)b)*NN*CIN;

  // A staging geometry: lane covers rows r0,r1 (16B each), inverse-swizzled source
  int r0 = wave*32 + (lane>>2);
  int r1 = r0 + 16;
  int ch0 = (lane&3) ^ ((r0>>1)&3);
  int ch1 = (lane&3) ^ ((r1>>1)&3);
  int wuni = __builtin_amdgcn_readfirstlane(wave);
  int wu  = wuni*1024;          // A-stage wave slice (elems)
  int wu2 = wuni*512;           // panel-stage wave slice (elems)
  const u16* pA0 = wp + (size_t)(co_base + r0)*CK + ch0*8;
  const u16* pA1 = wp + (size_t)(co_base + r1)*CK + ch1*8;

  // ---- panel gather pointers, computed ONCE per block (3 tasks/thread)
  const u16 *xp[3], *yp[3];
  { int tq4 = t >> 2;
    #pragma unroll
    for (int i=0;i<3;++i){
      int row = i*64 + tq4;                      // 0..191
      int lc = (t&3) ^ ((row>>1)&3);             // inverse swizzle chunk
      int q = (row*57) >> 10;                    // row/18 (row<192)
      int kk = row - q*18 - 1;                   // -1..16
      int n2 = nb0 - 1 + q;
      bool valid = (row < 180) && ((unsigned)n2 < (unsigned)NN) && ((unsigned)kk < (unsigned)KPTS);
      int j0 = 0, j1 = 0;
      if (valid){ int eo = b*POSB + n2*16 + kk; j0 = e[eo]; j1 = e[TOTPOS + eo]; }
      xp[i] = (valid ? xb + (size_t)j1*CIN : zrow) + lc*8;   // x via edge_index[1]
      yp[i] = (valid ? yb + (size_t)j0*CIN : zrow) + lc*8;   // y via edge_index[0]
    }
  }

  auto G16 = [&](const u16* g, u16* l){
    __builtin_amdgcn_global_load_lds((const __attribute__((address_space(1))) u32*)g,
                                     (__attribute__((address_space(3))) u32*)l, 16, 0, 0);
  };

  f32x4 acc[4][4];
  #pragma unroll
  for (int i=0;i<4;++i)
    #pragma unroll
    for (int j=0;j<4;++j) acc[i][j] = (f32x4){0.f,0.f,0.f,0.f};

  // prologue issue order: P0(3), P1(3), A0(2), A1(2), A2(2)
  G16(xp[0],    &pnl[wu2]);
  G16(xp[1],    &pnl[2048+wu2]);
  G16(xp[2],    &pnl[4096+wu2]);
  G16(xp[0]+32, &pnl[6144+wu2]);
  G16(xp[1]+32, &pnl[6144+2048+wu2]);
  G16(xp[2]+32, &pnl[6144+4096+wu2]);
  G16(pA0,      &als[wu]);      G16(pA1,      &als[wu+512]);
  G16(pA0+256,  &als[4096+wu]); G16(pA1+256,  &als[4096+wu+512]);
  G16(pA0+512,  &als[8192+wu]); G16(pA1+512,  &als[8192+wu+512]);

  int aoff[4];
  #pragma unroll
  for (int f=0; f<4; ++f) aoff[f] = SWZ(wr*64 + f*16 + l15, l4);
  int wc72l15 = wc*72 + l15;

  for (int c = 0; c < 8; ++c){
    const u16* pb = pnl + (c&1)*6144;
    int ca = c*32;
    int cc = (c < 7) ? (c+1) : 0;
    const u16 *q0,*q1,*q2;
    if (cc < 4){ q0 = xp[0]+cc*32;     q1 = xp[1]+cc*32;     q2 = xp[2]+cc*32; }
    else       { q0 = yp[0]+(cc-4)*32; q1 = yp[1]+(cc-4)*32; q2 = yp[2]+(cc-4)*32; }
    int pdst = (cc&1)*6144;
    bool doP = (c >= 1) & (c <= 6);             // P_1 prologued; P_8 doesn't exist
    #pragma unroll
    for (int tap = 0; tap < 9; ++tap){
      asm volatile("s_waitcnt vmcnt(4)" ::: "memory");
      __builtin_amdgcn_s_barrier();             // A[cur] (and panel at tap0) landed in all waves
      int abase = (tap%3)*4096;
      bf16x8 af[4], bv[4];
      #pragma unroll
      for (int f=0; f<4; ++f) af[f] = *(bf16x8*)&als[abase + aoff[f]];
      int kbc = (tap/3)*18 + (tap%3);           // (1+dn)*18 + (1+dk)
      #pragma unroll
      for (int f=0; f<4; ++f){
        int r = wc72l15 + kbc + f*18;           // panel row, 16 contiguous per fragment
        bv[f] = *(bf16x8*)&pb[r*32 + ((l4 ^ ((r>>1)&3))<<3)];
      }
      asm volatile("s_waitcnt lgkmcnt(0)" ::: "memory");
      __builtin_amdgcn_sched_barrier(0);
      __builtin_amdgcn_s_barrier();             // all reads done -> safe to overwrite
      int koff = ((tap+3)%9)*256 + ca + ((tap>5)?32:0);   // A_{s+3}; dummy at very end (harmless)
      G16(pA0 + koff, &als[abase + wu]);
      G16(pA1 + koff, &als[abase + wu + 512]);
      if (tap == 0 && doP){                     // panel for chunk c+1
        G16(q0, &pnl[pdst + wu2]);
        G16(q1, &pnl[pdst + 2048 + wu2]);
        G16(q2, &pnl[pdst + 4096 + wu2]);
      }
      __builtin_amdgcn_s_setprio(1);
      #pragma unroll
      for (int fm=0; fm<4; ++fm)
        #pragma unroll
        for (int fn=0; fn<4; ++fn)
          acc[fm][fn] = __builtin_amdgcn_mfma_f32_16x16x32_bf16(af[fm], bv[fn], acc[fm][fn], 0, 0, 0);
      __builtin_amdgcn_s_setprio(0);
    }
  }
  asm volatile("s_waitcnt vmcnt(0)" ::: "memory");   // drain dummy stages before LDS reuse
  __builtin_amdgcn_s_barrier();

  // ---- epilogue: bias + max over k (l15) + per-channel sum/sumsq
  float* fs = (float*)&als[0];           // fs[0..128) = sum, fs[128..256) = sumsq
  fs[t & 255] = 0.f;
  __syncthreads();

  #pragma unroll
  for (int fm=0; fm<4; ++fm){
    #pragma unroll
    for (int j=0; j<4; ++j){
      int ch = wr*64 + fm*16 + l4*4 + j;
      int co_g = co_base + ch;
      float bv2 = bias[co_g];
      float s = 0.f, q = 0.f;
      float mv[4];
      #pragma unroll
      for (int fn=0; fn<4; ++fn){
        float v = acc[fm][fn][j] + bv2;
        s += v; q += v*v; mv[fn] = v;
      }
      #pragma unroll
      for (int o=1; o<16; o<<=1){
        s += __shfl_xor(s, o, 64);
        q += __shfl_xor(q, o, 64);
        #pragma unroll
        for (int fn=0; fn<4; ++fn) mv[fn] = fmaxf(mv[fn], __shfl_xor(mv[fn], o, 64));
      }
      if (l15 == 0){
        atomicAdd(&fs[ch], s);
        atomicAdd(&fs[128 + ch], q);
        size_t rowb = ((size_t)(b*COUT + co_g)) << 12;
        #pragma unroll
        for (int fn=0; fn<4; ++fn)
          maxout[rowb + nb0 + wc*4 + fn] = mv[fn];
      }
    }
  }
  __syncthreads();
  if (t < 128)      atomicAdd(&ssum[co_base + t], fs[t]);
  else if (t < 256) atomicAdd(&ssq[co_base + t - 128], fs[t]);
}

// ---- 4. finalize BN scale/shift
__global__ void finalize_stats_kernel(const float* __restrict__ ssum, const float* __restrict__ ssq,
                                      const float* __restrict__ gamma, const float* __restrict__ beta,
                                      float* __restrict__ scale, float* __restrict__ shift){
  int co = threadIdx.x;
  float inv = 1.0f / (float)TOTPOS;
  float mean = ssum[co]*inv;
  float var = ssq[co]*inv - mean*mean;
  float sc = gamma[co] * rsqrtf(var + 1e-5f);
  scale[co] = sc;
  shift[co] = beta[co] - mean*sc;
}

// ---- 5. in-place BN + ReLU on maxout (valid since scale>0)
__global__ void bn_finish_kernel(float* __restrict__ out, const float* __restrict__ scale,
                                 const float* __restrict__ shift){
  int t = blockIdx.x*256 + threadIdx.x;
  int co = (t >> 12) & 255;
  float v = out[t];
  out[t] = fmaxf(fmaf(scale[co], v, shift[co]), 0.f);
}

extern "C" void kernel_launch(void* const* d_in, const int* in_sizes, int n_in,
                              void* d_out, int out_size, void* d_ws, size_t ws_size,
                              hipStream_t stream){
  const float* x = (const float*)d_in[0];
  const float* y = (const float*)d_in[1];
  const int*   e = (const int*)d_in[2];
  const float* w = (const float*)d_in[3];
  const float* bias = (const float*)d_in[4];
  const float* gamma = (const float*)d_in[5];
  const float* beta  = (const float*)d_in[6];
  float* out = (float*)d_out;

  char* ws = (char*)d_ws;                  // total footprint: ~9.6 MB
  u16*   wp    = (u16*)(ws);               // 1,179,648 B
  float* ssum  = (float*)(ws + 1179648);   // 1 KB
  float* ssq   = (float*)(ws + 1180672);   // 1 KB
  u16*   zrow  = (u16*)(ws + 1181696);     // 1 KB zero row
  float* scale = (float*)(ws + 1182720);   // 1 KB
  float* shift = (float*)(ws + 1183744);   // 1 KB
  u16*   xt    = (u16*)(ws + 1184768);     // 4 MB
  u16*   yt    = (u16*)(ws + 5379072);     // 4 MB  (end: 9,573,376)

  hipMemsetAsync(ssum, 0, 3072, stream);   // zero ssum+ssq+zrow every call (deterministic)

  pack_w_kernel<<<2304, 256, 0, stream>>>(w, wp);
  dim3 tg(NN/64, CIN/32, NB);
  transpose_cast_kernel<<<tg, 256, 0, stream>>>(x, y, xt, yt);
  conv_gemm_kernel<<<4096, 256, 0, stream>>>(wp, e, xt, yt, zrow, bias, ssum, ssq, out);
  finalize_stats_kernel<<<1, COUT, 0, stream>>>(ssum, ssq, gamma, beta, scale, shift);
  bn_finish_kernel<<<out_size/256, 256, 0, stream>>>(out, scale, shift);
}